// Round 5
// baseline (348.391 us; speedup 1.0000x reference)
//
#include <hip/hip_runtime.h>
#include <hip/hip_bf16.h>
#include <hip/hip_cooperative_groups.h>

namespace cg = cooperative_groups;

#define NEG_SLOPE 0.2f
#define THR    256   // threads per block
#define NBLK   256   // blocks (1 per CU -> cooperative-safe)
#define B1CAP  32    // per-block bucket cap, target edges (exp ~0.08/block)
#define B2CAP  64    // per-block bucket cap, S edges (exp ~2/block)
#define CAP1   512   // total edges into target (realistic ~21)
#define CAPS   64    // unique source nodes incl target (realistic ~21)
#define MAXDEG 256   // per-node in-degree cap in layer-1

// bf16 bits (as ushort) -> float
__device__ __forceinline__ float us2f(unsigned short s) {
    union { unsigned int u; float f; } c;
    c.u = ((unsigned int)s) << 16;
    return c.f;
}
template<bool F32>
__device__ __forceinline__ float tld(const void* p, int i) {
    if (F32) return ((const float*)p)[i];
    return us2f(((const unsigned short*)p)[i]);
}

template<bool F32>
__device__ void mono_body(
    const void* __restrict__ x, const int* __restrict__ src,
    const int* __restrict__ dst, const void* __restrict__ ea, int tgt0,
    const void* Wl1, const void* bl1, const void* Wr1, const void* br1,
    const void* We1, const void* att1, const void* b1,
    const void* Wl2, const void* bl2, const void* Wr2, const void* br2,
    const void* We2, const void* att2, const void* b2v,
    const void* Wfc, const void* bfc,
    void* __restrict__ out, int E, int* __restrict__ ws)
{
    cg::grid_group grid = cg::this_grid();
    const int tid = threadIdx.x, bid = blockIdx.x;
    const int gid = bid * THR + tid, gs = NBLK * THR;
    const int E4 = E >> 2, rem = E & 3;

    // ---- workspace map (ints) ----
    // ws[0]=c1 ws[1]=ns ; ((float*)ws)[4]=mean
    float* parts = (float*)(ws + 8);
    int*   b1cnt = ws + 8 + NBLK;
    int*   b1src = b1cnt + NBLK;
    float* b1ea  = (float*)(b1src + NBLK * B1CAP);
    int*   b2cnt = (int*)(b1ea + NBLK * B1CAP);
    int*   b2src = b2cnt + NBLK;
    int*   b2dst = b2src + NBLK * B2CAP;
    float* b2ea  = (float*)(b2dst + NBLK * B2CAP);
    int*   l1src = (int*)(b2ea + NBLK * B2CAP);
    float* l1ea  = (float*)(l1src + CAP1);
    int*   slist = (int*)(l1ea + CAP1);
    float* xl2   = (float*)(slist + CAPS);
    float* xr2   = xl2 + CAPS * 128;

    // ---- shared ----
    __shared__ int   sCnt, sC1, sNs;
    __shared__ float sMean;
    __shared__ float sRed[4];
    __shared__ int   sIb[B2CAP];  __shared__ int sIb2[B2CAP];
    __shared__ float sFb[B2CAP];
    __shared__ int   sPfx[THR];
    __shared__ int   sTmp[CAP1];
    __shared__ int   sS[CAPS];
    __shared__ float sWl[128], sBl[128], sWe[128], sAtt[128], sB1[128], sBase[128];
    __shared__ float sXs[MAXDEG], sEa2[MAXDEG], sL0[MAXDEG], sL1[MAXDEG], sH[128];
    __shared__ float sl0[CAP1], sl1[CAP1]; __shared__ int sslot[CAP1];
    __shared__ float semb[128];

    // ======================= Phase A: scan1 ===============================
    if (tid == 0) sCnt = 0;
    __syncthreads();
    {
        float sum = 0.f;
        for (int j = gid; j < E4; j += gs) {
            int4 d4 = ((const int4*)dst)[j];
            float v0, v1, v2, v3;
            if (F32) {
                float4 e4 = ((const float4*)ea)[j];
                v0 = e4.x; v1 = e4.y; v2 = e4.z; v3 = e4.w;
            } else {
                ushort4 u4 = ((const ushort4*)ea)[j];
                v0 = us2f(u4.x); v1 = us2f(u4.y); v2 = us2f(u4.z); v3 = us2f(u4.w);
            }
            sum += (v0 + v1) + (v2 + v3);
            int base = 4 * j;
            if (d4.x == tgt0) { int p = atomicAdd(&sCnt, 1); if (p < B1CAP) { sIb[p] = src[base+0]; sFb[p] = v0; } }
            if (d4.y == tgt0) { int p = atomicAdd(&sCnt, 1); if (p < B1CAP) { sIb[p] = src[base+1]; sFb[p] = v1; } }
            if (d4.z == tgt0) { int p = atomicAdd(&sCnt, 1); if (p < B1CAP) { sIb[p] = src[base+2]; sFb[p] = v2; } }
            if (d4.w == tgt0) { int p = atomicAdd(&sCnt, 1); if (p < B1CAP) { sIb[p] = src[base+3]; sFb[p] = v3; } }
        }
        if (gid < rem) {
            int i = E4 * 4 + gid;
            float v = tld<F32>(ea, i);
            sum += v;
            if (dst[i] == tgt0) { int p = atomicAdd(&sCnt, 1); if (p < B1CAP) { sIb[p] = src[i]; sFb[p] = v; } }
        }
        for (int o = 32; o > 0; o >>= 1) sum += __shfl_down(sum, o);
        if ((tid & 63) == 0) sRed[tid >> 6] = sum;
        __syncthreads();
        if (tid == 0) parts[bid] = sRed[0] + sRed[1] + sRed[2] + sRed[3];
        int bc = sCnt < B1CAP ? sCnt : B1CAP;
        if (tid == 0) b1cnt[bid] = bc;
        if (tid < bc) { b1src[bid * B1CAP + tid] = sIb[tid]; b1ea[bid * B1CAP + tid] = sFb[tid]; }
    }
    __threadfence();
    grid.sync();

    // ======================= Phase B: build (block 0) =====================
    if (bid == 0) {
        int c = b1cnt[tid]; if (c > B1CAP) c = B1CAP;
        sPfx[tid] = c;
        __syncthreads();
        for (int o = 1; o < THR; o <<= 1) {
            int v = (tid >= o) ? sPfx[tid - o] : 0;
            __syncthreads();
            sPfx[tid] += v;
            __syncthreads();
        }
        int base = sPfx[tid] - c;
        int c1tot = sPfx[THR - 1];
        for (int j = 0; j < c; j++) {
            int p = base + j;
            if (p < CAP1 - 1) { l1src[p] = b1src[tid * B1CAP + j]; l1ea[p] = b1ea[tid * B1CAP + j]; }
        }
        float s = 0.f;
        for (int i = tid; i < NBLK; i += THR) s += parts[i];
        for (int o = 32; o > 0; o >>= 1) s += __shfl_down(s, o);
        if ((tid & 63) == 0) sRed[tid >> 6] = s;
        __syncthreads();
        if (tid == 0) {
            float mean = (sRed[0] + sRed[1] + sRed[2] + sRed[3]) / (float)E;
            sMean = mean;
            int c1 = c1tot < CAP1 - 1 ? c1tot : CAP1 - 1;
            l1src[c1] = tgt0; l1ea[c1] = mean;   // target self-loop
            sC1 = c1 + 1;
        }
        __syncthreads();
        int c1 = sC1;
        for (int e = tid; e < c1; e += THR) sTmp[e] = l1src[e];
        __syncthreads();
        if (tid == 0) {
            int nsl = 0;
            for (int e = 0; e < c1; e++) {
                int sv = sTmp[e];
                bool f = false;
                for (int j = 0; j < nsl; j++) if (sS[j] == sv) { f = true; break; }
                if (!f && nsl < CAPS) { sS[nsl] = sv; nsl++; }
            }
            for (int j = 0; j < nsl; j++) slist[j] = sS[j];
            ws[0] = c1; ws[1] = nsl; ((float*)ws)[4] = sMean;
        }
        __threadfence();
    }
    grid.sync();

    // ======================= Phase C: scan2 ===============================
    if (tid == 0) { sNs = ws[1] > CAPS ? CAPS : ws[1]; sCnt = 0; }
    if (tid < CAPS) sS[tid] = slist[tid];
    __syncthreads();
    {
        int ns = sNs;
        #define CHECK(dv, idx)                                                 \
            do {                                                               \
                for (int j_ = 0; j_ < ns; j_++) {                              \
                    if (sS[j_] == (dv)) {                                      \
                        int p_ = atomicAdd(&sCnt, 1);                          \
                        if (p_ < B2CAP) {                                      \
                            sIb[p_] = src[idx]; sIb2[p_] = (dv);               \
                            sFb[p_] = tld<F32>(ea, idx);                       \
                        }                                                      \
                        break;                                                 \
                    }                                                          \
                }                                                              \
            } while (0)
        for (int j = gid; j < E4; j += gs) {
            int4 d4 = ((const int4*)dst)[j];
            int base = 4 * j;
            CHECK(d4.x, base + 0);
            CHECK(d4.y, base + 1);
            CHECK(d4.z, base + 2);
            CHECK(d4.w, base + 3);
        }
        if (gid < rem) { int i = E4 * 4 + gid; CHECK(dst[i], i); }
        #undef CHECK
        __syncthreads();
        int bc = sCnt < B2CAP ? sCnt : B2CAP;
        if (tid == 0) b2cnt[bid] = bc;
        if (tid < bc) {
            b2src[bid * B2CAP + tid] = sIb[tid];
            b2dst[bid * B2CAP + tid] = sIb2[tid];
            b2ea [bid * B2CAP + tid] = sFb[tid];
        }
    }
    __threadfence();
    grid.sync();

    // ======================= Phase D: layer-1 (blocks 0..ns-1) ===========
    {
        int nsv = ws[1]; if (nsv > CAPS) nsv = CAPS;
        float mean = ((float*)ws)[4];
        if (bid < nsv) {
            int s = slist[bid];
            if (tid < 128) {
                sWl[tid] = tld<F32>(Wl1, tid);  sBl[tid] = tld<F32>(bl1, tid);
                sWe[tid] = tld<F32>(We1, tid);  sAtt[tid] = tld<F32>(att1, tid);
                sB1[tid] = tld<F32>(b1, tid);
                float xt = tld<F32>(x, s);
                sBase[tid] = xt * tld<F32>(Wr1, tid) + tld<F32>(br1, tid);
            }
            if (tid == 0) { sCnt = 1; sXs[0] = tld<F32>(x, s); sEa2[0] = mean; }  // self-loop
            __syncthreads();
            {   // gather this node's edges from all 256 buckets (thread t -> bucket t)
                int c = b2cnt[tid]; if (c > B2CAP) c = B2CAP;
                for (int j = 0; j < c; j++) {
                    if (b2dst[tid * B2CAP + j] == s) {
                        int p = atomicAdd(&sCnt, 1);
                        if (p < MAXDEG) {
                            sXs[p] = tld<F32>(x, b2src[tid * B2CAP + j]);
                            sEa2[p] = b2ea[tid * B2CAP + j];
                        }
                    }
                }
            }
            __syncthreads();
            int deg = sCnt < MAXDEG ? sCnt : MAXDEG;
            for (int i = tid; i < deg; i += THR) {
                float xs = sXs[i], eav = sEa2[i];
                float l0 = 0.f, l1v = 0.f;
                #pragma unroll 8
                for (int c2 = 0; c2 < 128; c2++) {
                    float v = xs * sWl[c2] + sBl[c2] + sBase[c2] + eav * sWe[c2];
                    v = v > 0.f ? v : NEG_SLOPE * v;
                    float w = v * sAtt[c2];
                    if (c2 < 64) l0 += w; else l1v += w;
                }
                sL0[i] = l0; sL1[i] = l1v;
            }
            __syncthreads();
            if (tid == 0) {   // softmax over <= ~50 edges
                float m0 = -1e30f, m1 = -1e30f;
                for (int i = 0; i < deg; i++) { m0 = fmaxf(m0, sL0[i]); m1 = fmaxf(m1, sL1[i]); }
                float s0 = 0.f, s1 = 0.f;
                for (int i = 0; i < deg; i++) {
                    sL0[i] = __expf(sL0[i] - m0); s0 += sL0[i];
                    sL1[i] = __expf(sL1[i] - m1); s1 += sL1[i];
                }
                float r0 = 1.f / s0, r1 = 1.f / s1;
                for (int i = 0; i < deg; i++) { sL0[i] *= r0; sL1[i] *= r1; }
            }
            __syncthreads();
            if (tid < 128) {   // aggregate + bias + relu
                bool hi = tid >= 64;
                float acc = 0.f;
                for (int i = 0; i < deg; i++) {
                    float a = hi ? sL1[i] : sL0[i];
                    acc += a * (sXs[i] * sWl[tid] + sBl[tid]);
                }
                acc += sB1[tid];
                sH[tid] = fmaxf(acc, 0.f);
            }
            __syncthreads();
            if (tid < 128) {   // xl2 = h1 @ Wl2 + bl2 ; xr2 for target only
                float acc = tld<F32>(bl2, tid);
                #pragma unroll 16
                for (int k = 0; k < 128; k++) acc += sH[k] * tld<F32>(Wl2, k * 128 + tid);
                xl2[bid * 128 + tid] = acc;
                if (s == tgt0) {
                    float a2 = tld<F32>(br2, tid);
                    #pragma unroll 16
                    for (int k = 0; k < 128; k++) a2 += sH[k] * tld<F32>(Wr2, k * 128 + tid);
                    xr2[tid] = a2;
                }
            }
        }
    }
    __threadfence();
    grid.sync();

    // ======================= Phase E: layer-2 + FC (block 0) ==============
    if (bid == 0) {
        int c1 = ws[0]; if (c1 > CAP1) c1 = CAP1;
        int ns = ws[1]; if (ns > CAPS) ns = CAPS;
        for (int e = tid; e < c1; e += THR) {
            int sv = l1src[e];
            int slot = 0;
            for (int j = 0; j < ns; j++) if (sS[j] == sv) { slot = j; break; }
            sslot[e] = slot;
        }
        __syncthreads();
        float xr = 0.f, we = 0.f, at = 0.f;
        if (tid < 128) { xr = xr2[tid]; we = tld<F32>(We2, tid); at = tld<F32>(att2, tid); }
        for (int e = 0; e < c1; e++) {
            float w = 0.f;
            if (tid < 128) {
                float v = xl2[sslot[e] * 128 + tid] + xr + l1ea[e] * we;
                v = v > 0.f ? v : NEG_SLOPE * v;
                w = v * at;
            }
            for (int o = 32; o > 0; o >>= 1) w += __shfl_down(w, o);
            if (tid == 0)  sl0[e] = w;
            if (tid == 64) sl1[e] = w;
        }
        __syncthreads();
        if (tid == 0) {
            float m0 = -1e30f, m1 = -1e30f;
            for (int e = 0; e < c1; e++) { m0 = fmaxf(m0, sl0[e]); m1 = fmaxf(m1, sl1[e]); }
            float s0 = 0.f, s1 = 0.f;
            for (int e = 0; e < c1; e++) {
                sl0[e] = __expf(sl0[e] - m0); s0 += sl0[e];
                sl1[e] = __expf(sl1[e] - m1); s1 += sl1[e];
            }
            float r0 = 1.f / s0, r1 = 1.f / s1;
            for (int e = 0; e < c1; e++) { sl0[e] *= r0; sl1[e] *= r1; }
        }
        __syncthreads();
        if (tid < 128) {
            bool hi = tid >= 64;
            float acc = tld<F32>(b2v, tid);
            for (int e = 0; e < c1; e++) {
                float a = hi ? sl1[e] : sl0[e];
                acc += a * xl2[sslot[e] * 128 + tid];
            }
            semb[tid] = acc;
        }
        __syncthreads();
        if (tid < 128) {
            float o = tld<F32>(bfc, tid);
            #pragma unroll 16
            for (int c2 = 0; c2 < 128; c2++) o += semb[c2] * tld<F32>(Wfc, c2 * 128 + tid);
            if (F32) ((float*)out)[tid] = o;
            else     ((__hip_bfloat16*)out)[tid] = __float2bfloat16(o);
        }
    }
}

__global__ void __launch_bounds__(THR)
k_mono(const void* x, const int* src, const int* dst, const void* ea,
       const int* tgt,
       const void* Wl1, const void* bl1, const void* Wr1, const void* br1,
       const void* We1, const void* att1, const void* b1,
       const void* Wl2, const void* bl2, const void* Wr2, const void* br2,
       const void* We2, const void* att2, const void* b2v,
       const void* Wfc, const void* bfc,
       void* out, int E, int* ws)
{
    // dtype detect: every block independently (L2-cached after first touch).
    __shared__ int sWeird;
    if (threadIdx.x == 0) sWeird = 0;
    __syncthreads();
    {
        const unsigned short* u = (const unsigned short*)x;
        int c = 0;
        for (int i = threadIdx.x; i < 2048; i += THR) {
            int e2 = (u[i] >> 7) & 0xFF;
            if (e2 == 0 || e2 >= 0xC0) c++;
        }
        for (int o = 32; o > 0; o >>= 1) c += __shfl_down(c, o);
        if ((threadIdx.x & 63) == 0) atomicAdd(&sWeird, c);
    }
    __syncthreads();
    bool f32 = sWeird >= 64;   // grid-uniform (same data, same arithmetic)
    int t = tgt[0];
    if (f32) mono_body<true >(x, src, dst, ea, t, Wl1, bl1, Wr1, br1, We1, att1, b1,
                              Wl2, bl2, Wr2, br2, We2, att2, b2v, Wfc, bfc, out, E, ws);
    else     mono_body<false>(x, src, dst, ea, t, Wl1, bl1, Wr1, br1, We1, att1, b1,
                              Wl2, bl2, Wr2, br2, We2, att2, b2v, Wfc, bfc, out, E, ws);
}

// ---------------------------------------------------------------------------
extern "C" void kernel_launch(void* const* d_in, const int* in_sizes, int n_in,
                              void* d_out, int out_size, void* d_ws, size_t ws_size,
                              hipStream_t stream) {
    const void* x    = d_in[0];
    const int*  eidx = (const int*)d_in[1];
    const void* eattr= d_in[2];
    const int*  tgt  = (const int*)d_in[3];
    const void* Wl1 = d_in[4],  *bl1 = d_in[5],  *Wr1 = d_in[6],  *br1 = d_in[7];
    const void* We1 = d_in[8],  *att1= d_in[9],  *b1  = d_in[10];
    const void* Wl2 = d_in[11], *bl2 = d_in[12], *Wr2 = d_in[13], *br2 = d_in[14];
    const void* We2 = d_in[15], *att2= d_in[16], *b2v = d_in[17];
    const void* Wfc = d_in[18], *bfc = d_in[19];

    int E = in_sizes[1] / 2;
    const int* src = eidx;
    const int* dst = eidx + E;
    int* ws = (int*)d_ws;

    void* kargs[] = {
        (void*)&x, (void*)&src, (void*)&dst, (void*)&eattr, (void*)&tgt,
        (void*)&Wl1, (void*)&bl1, (void*)&Wr1, (void*)&br1,
        (void*)&We1, (void*)&att1, (void*)&b1,
        (void*)&Wl2, (void*)&bl2, (void*)&Wr2, (void*)&br2,
        (void*)&We2, (void*)&att2, (void*)&b2v,
        (void*)&Wfc, (void*)&bfc,
        (void*)&d_out, (void*)&E, (void*)&ws,
    };
    hipLaunchCooperativeKernel((void*)k_mono, dim3(NBLK), dim3(THR),
                               kargs, 0, stream);
}

// Round 6
// 198.358 us; speedup vs baseline: 1.7564x; 1.7564x over previous
//
#include <hip/hip_runtime.h>
#include <hip/hip_bf16.h>

#define NEG_SLOPE 0.2f
#define THR    256   // threads per block
#define NB1    512   // scan1 blocks
#define NB2    512   // scan2 blocks
#define B1CAP  16    // per-block bucket cap, target edges (exp ~0.04/block)
#define B2CAP  32    // per-block bucket cap, S edges (exp ~1/block)
#define CAP1   512   // total edges into target (realistic ~21)
#define CAPS   64    // unique source nodes incl target (realistic ~21)
#define MAXDEG 256   // per-node in-degree cap in layer-1
#define NTAIL  (CAPS + 1)

// ws header: W[0]=c1 W[1]=ns W[2]=flag W[3]=f32 W[4]=doneCnt W[5]=mean(bits)
#define OFF_PARTS  8
#define OFF_B1CNT  (OFF_PARTS + NB1)
#define OFF_B1SRC  (OFF_B1CNT + NB1)
#define OFF_B1EA   (OFF_B1SRC + NB1 * B1CAP)
#define OFF_B2CNT  (OFF_B1EA + NB1 * B1CAP)
#define OFF_B2SRC  (OFF_B2CNT + NB2)
#define OFF_B2DST  (OFF_B2SRC + NB2 * B2CAP)
#define OFF_B2EA   (OFF_B2DST + NB2 * B2CAP)
#define OFF_L1SRC  (OFF_B2EA + NB2 * B2CAP)
#define OFF_L1EA   (OFF_L1SRC + CAP1)
#define OFF_SLIST  (OFF_L1EA + CAP1)
#define OFF_XL2    (OFF_SLIST + CAPS)
#define OFF_XR2    (OFF_XL2 + CAPS * 128)

__device__ __forceinline__ float us2f(unsigned short s) {
    union { unsigned int u; float f; } c;
    c.u = ((unsigned int)s) << 16;
    return c.f;
}
template<bool F32>
__device__ __forceinline__ float tld(const void* p, int i) {
    if (F32) return ((const float*)p)[i];
    return us2f(((const unsigned short*)p)[i]);
}
__device__ __forceinline__ int ald_i(const int* p) {
    return __hip_atomic_load(p, __ATOMIC_RELAXED, __HIP_MEMORY_SCOPE_AGENT);
}
__device__ __forceinline__ float ald_f(const float* p) {
    return __hip_atomic_load(p, __ATOMIC_RELAXED, __HIP_MEMORY_SCOPE_AGENT);
}

// ---------------------------------------------------------------------------
// K1: dtype detect (per-block) + bucketed scan for dst==target + ea partials.
template<bool F32>
__device__ void scan1_body(const int* __restrict__ src, const int* __restrict__ dst,
                           const void* __restrict__ ea, int t, int E,
                           int* __restrict__ W) {
    __shared__ float sRed[4];
    __shared__ int   sCnt;
    __shared__ int   sIb[B1CAP];
    __shared__ float sFb[B1CAP];
    const int tid = threadIdx.x, bid = blockIdx.x;
    const int gid = bid * THR + tid, gs = NB1 * THR;
    const int E4 = E >> 2, rem = E & 3;
    float* parts = (float*)(W + OFF_PARTS);
    int*   b1cnt = W + OFF_B1CNT;
    int*   b1src = W + OFF_B1SRC;
    float* b1ea  = (float*)(W + OFF_B1EA);

    if (tid == 0) sCnt = 0;
    __syncthreads();
    float sum = 0.f;
    for (int j = gid; j < E4; j += gs) {
        int4 d4 = ((const int4*)dst)[j];
        float v0, v1, v2, v3;
        if (F32) {
            float4 e4 = ((const float4*)ea)[j];
            v0 = e4.x; v1 = e4.y; v2 = e4.z; v3 = e4.w;
        } else {
            ushort4 u4 = ((const ushort4*)ea)[j];
            v0 = us2f(u4.x); v1 = us2f(u4.y); v2 = us2f(u4.z); v3 = us2f(u4.w);
        }
        sum += (v0 + v1) + (v2 + v3);
        int base = 4 * j;
        if (d4.x == t) { int p = atomicAdd(&sCnt, 1); if (p < B1CAP) { sIb[p] = src[base+0]; sFb[p] = v0; } }
        if (d4.y == t) { int p = atomicAdd(&sCnt, 1); if (p < B1CAP) { sIb[p] = src[base+1]; sFb[p] = v1; } }
        if (d4.z == t) { int p = atomicAdd(&sCnt, 1); if (p < B1CAP) { sIb[p] = src[base+2]; sFb[p] = v2; } }
        if (d4.w == t) { int p = atomicAdd(&sCnt, 1); if (p < B1CAP) { sIb[p] = src[base+3]; sFb[p] = v3; } }
    }
    if (gid < rem) {
        int i = E4 * 4 + gid;
        float v = tld<F32>(ea, i);
        sum += v;
        if (dst[i] == t) { int p = atomicAdd(&sCnt, 1); if (p < B1CAP) { sIb[p] = src[i]; sFb[p] = v; } }
    }
    for (int o = 32; o > 0; o >>= 1) sum += __shfl_down(sum, o);
    if ((tid & 63) == 0) sRed[tid >> 6] = sum;
    __syncthreads();
    if (tid == 0) parts[bid] = sRed[0] + sRed[1] + sRed[2] + sRed[3];
    int bc = sCnt < B1CAP ? sCnt : B1CAP;
    if (tid == 0) b1cnt[bid] = bc;
    if (tid < bc) { b1src[bid * B1CAP + tid] = sIb[tid]; b1ea[bid * B1CAP + tid] = sFb[tid]; }
}

__global__ void __launch_bounds__(THR)
k_scan1(const void* __restrict__ x, const int* __restrict__ src,
        const int* __restrict__ dst, const void* __restrict__ ea,
        const int* __restrict__ tgt, int E, int* __restrict__ W) {
    // per-block dtype detect (x head is L2/LLC-resident after first block)
    __shared__ int sWeird;
    if (threadIdx.x == 0) sWeird = 0;
    __syncthreads();
    {
        const unsigned short* u = (const unsigned short*)x;
        int c = 0;
        for (int i = threadIdx.x; i < 2048; i += THR) {
            int e2 = (u[i] >> 7) & 0xFF;
            if (e2 == 0 || e2 >= 0xC0) c++;
        }
        for (int o = 32; o > 0; o >>= 1) c += __shfl_down(c, o);
        if ((threadIdx.x & 63) == 0) atomicAdd(&sWeird, c);
    }
    __syncthreads();
    bool f32 = sWeird >= 64;
    if (blockIdx.x == 0 && threadIdx.x == 0) { W[2] = 0; W[3] = f32 ? 1 : 0; }
    int t = tgt[0];
    if (f32) scan1_body<true >(src, dst, ea, t, E, W);
    else     scan1_body<false>(src, dst, ea, t, E, W);
}

// ---------------------------------------------------------------------------
// K2: block 0 builds (compact l1, mean, unique S) then releases; all blocks
//     bucket-scan for edges whose dst is in S.
template<bool F32>
__device__ void scan2_body(const int* __restrict__ src, const int* __restrict__ dst,
                           const void* __restrict__ ea, int tgt0, int E,
                           int* __restrict__ W) {
    __shared__ int   sS[CAPS];
    __shared__ int   sNs, sCnt;
    __shared__ int   sPfx[THR];
    __shared__ float sRed[4];
    __shared__ int   sIb[B2CAP], sIb2[B2CAP];
    __shared__ float sFb[B2CAP];
    const int tid = threadIdx.x, bid = blockIdx.x;
    const int gid = bid * THR + tid, gs = NB2 * THR;
    const int E4 = E >> 2, rem = E & 3;
    float* parts = (float*)(W + OFF_PARTS);
    int*   b1cnt = W + OFF_B1CNT;
    int*   b1src = W + OFF_B1SRC;
    float* b1ea  = (float*)(W + OFF_B1EA);
    int*   b2cnt = W + OFF_B2CNT;
    int*   b2src = W + OFF_B2SRC;
    int*   b2dst = W + OFF_B2DST;
    float* b2ea  = (float*)(W + OFF_B2EA);
    int*   l1src = W + OFF_L1SRC;
    float* l1ea  = (float*)(W + OFF_L1EA);
    int*   slist = W + OFF_SLIST;

    if (bid == 0) {
        // ---- build: compact 512 buckets (thread t handles 2t, 2t+1) ----
        int c0 = b1cnt[2*tid];     if (c0 > B1CAP) c0 = B1CAP;
        int c1b = b1cnt[2*tid+1];  if (c1b > B1CAP) c1b = B1CAP;
        int c = c0 + c1b;
        sPfx[tid] = c;
        __syncthreads();
        for (int o = 1; o < THR; o <<= 1) {
            int v = (tid >= o) ? sPfx[tid - o] : 0;
            __syncthreads();
            sPfx[tid] += v;
            __syncthreads();
        }
        int base = sPfx[tid] - c;
        int c1tot = sPfx[THR - 1];
        for (int j = 0; j < c0; j++) {
            int p = base + j;
            if (p < CAP1 - 1) { l1src[p] = b1src[2*tid*B1CAP + j]; l1ea[p] = b1ea[2*tid*B1CAP + j]; }
        }
        for (int j = 0; j < c1b; j++) {
            int p = base + c0 + j;
            if (p < CAP1 - 1) { l1src[p] = b1src[(2*tid+1)*B1CAP + j]; l1ea[p] = b1ea[(2*tid+1)*B1CAP + j]; }
        }
        // ---- mean(edge_attr) ----
        float s = parts[tid] + parts[tid + THR];
        for (int o = 32; o > 0; o >>= 1) s += __shfl_down(s, o);
        if ((tid & 63) == 0) sRed[tid >> 6] = s;
        __syncthreads();
        if (tid == 0) {
            float mean = (sRed[0] + sRed[1] + sRed[2] + sRed[3]) / (float)E;
            int c1 = c1tot < CAP1 - 1 ? c1tot : CAP1 - 1;
            l1src[c1] = tgt0; l1ea[c1] = mean;      // target self-loop
            c1++;
            // unique S (serial, ~21 entries)
            int nsl = 0;
            for (int e = 0; e < c1; e++) {
                int sv = l1src[e];
                bool f = false;
                for (int j = 0; j < nsl; j++) if (sS[j] == sv) { f = true; break; }
                if (!f && nsl < CAPS) { sS[nsl] = sv; nsl++; }
            }
            for (int j = 0; j < nsl; j++) slist[j] = sS[j];
            W[0] = c1; W[1] = nsl; W[4] = 0;
            ((float*)W)[5] = mean;
            sNs = nsl;
            __threadfence();
            __hip_atomic_store(&W[2], 1, __ATOMIC_RELEASE, __HIP_MEMORY_SCOPE_AGENT);
        }
        __syncthreads();
    } else {
        if (tid == 0) {
            while (__hip_atomic_load(&W[2], __ATOMIC_ACQUIRE, __HIP_MEMORY_SCOPE_AGENT) == 0)
                __builtin_amdgcn_s_sleep(2);
            sNs = ald_i(&W[1]) > CAPS ? CAPS : ald_i(&W[1]);
        }
        __syncthreads();
        if (tid < CAPS && tid < sNs) sS[tid] = ald_i(&slist[tid]);
        __syncthreads();
    }
    if (tid == 0) sCnt = 0;
    __syncthreads();
    int ns = sNs;

    #define CHECK(dv, idx)                                                     \
        do {                                                                   \
            for (int j_ = 0; j_ < ns; j_++) {                                  \
                if (sS[j_] == (dv)) {                                          \
                    int p_ = atomicAdd(&sCnt, 1);                              \
                    if (p_ < B2CAP) {                                          \
                        sIb[p_] = src[idx]; sIb2[p_] = (dv);                   \
                        sFb[p_] = tld<F32>(ea, idx);                           \
                    }                                                          \
                    break;                                                     \
                }                                                              \
            }                                                                  \
        } while (0)
    for (int j = gid; j < E4; j += gs) {
        int4 d4 = ((const int4*)dst)[j];
        int base = 4 * j;
        CHECK(d4.x, base + 0);
        CHECK(d4.y, base + 1);
        CHECK(d4.z, base + 2);
        CHECK(d4.w, base + 3);
    }
    if (gid < rem) { int i = E4 * 4 + gid; CHECK(dst[i], i); }
    #undef CHECK
    __syncthreads();
    int bc = sCnt < B2CAP ? sCnt : B2CAP;
    if (tid == 0) b2cnt[bid] = bc;
    if (tid < bc) {
        b2src[bid * B2CAP + tid] = sIb[tid];
        b2dst[bid * B2CAP + tid] = sIb2[tid];
        b2ea [bid * B2CAP + tid] = sFb[tid];
    }
}

__global__ void __launch_bounds__(THR)
k_scan2(const int* __restrict__ src, const int* __restrict__ dst,
        const void* __restrict__ ea, const int* __restrict__ tgt,
        int E, int* __restrict__ W) {
    int t = tgt[0];
    if (W[3]) scan2_body<true >(src, dst, ea, t, E, W);
    else      scan2_body<false>(src, dst, ea, t, E, W);
}

// ---------------------------------------------------------------------------
// K3: blocks 0..ns-1 = layer-1 per S-node; block CAPS = finisher (layer-2+FC).
template<bool F32>
__device__ void tail_body(
    const void* __restrict__ x, int tgt0,
    const void* Wl1, const void* bl1, const void* Wr1, const void* br1,
    const void* We1, const void* att1, const void* b1,
    const void* Wl2, const void* bl2, const void* Wr2, const void* br2,
    const void* We2, const void* att2, const void* b2v,
    const void* Wfc, const void* bfc,
    void* __restrict__ out, int* __restrict__ W)
{
    const int tid = threadIdx.x, bid = blockIdx.x;
    int*   b2cnt = W + OFF_B2CNT;
    int*   b2src = W + OFF_B2SRC;
    int*   b2dst = W + OFF_B2DST;
    float* b2ea  = (float*)(W + OFF_B2EA);
    int*   l1src = W + OFF_L1SRC;
    float* l1ea  = (float*)(W + OFF_L1EA);
    int*   slist = W + OFF_SLIST;
    float* xl2   = (float*)(W + OFF_XL2);
    float* xr2   = (float*)(W + OFF_XR2);

    int ns = W[1]; if (ns > CAPS) ns = CAPS;
    int c1 = W[0]; if (c1 > CAP1) c1 = CAP1;
    float mean = ((float*)W)[5];

    if (bid < ns) {
        // ---------------- layer-1 for node s ----------------
        __shared__ float sWl[128], sBl[128], sWe[128], sAtt[128], sB1[128], sBase[128];
        __shared__ float sXs[MAXDEG], sEa2[MAXDEG], sL0[MAXDEG], sL1[MAXDEG], sH[128];
        __shared__ int sCnt;
        int s = slist[bid];
        if (tid < 128) {
            sWl[tid] = tld<F32>(Wl1, tid);  sBl[tid] = tld<F32>(bl1, tid);
            sWe[tid] = tld<F32>(We1, tid);  sAtt[tid] = tld<F32>(att1, tid);
            sB1[tid] = tld<F32>(b1, tid);
            float xt = tld<F32>(x, s);
            sBase[tid] = xt * tld<F32>(Wr1, tid) + tld<F32>(br1, tid);
        }
        if (tid == 0) { sCnt = 1; sXs[0] = tld<F32>(x, s); sEa2[0] = mean; }  // self-loop
        __syncthreads();
        {   // gather from 512 buckets: thread t handles buckets t and t+256
            for (int bk = tid; bk < NB2; bk += THR) {
                int c = b2cnt[bk]; if (c > B2CAP) c = B2CAP;
                for (int j = 0; j < c; j++) {
                    if (b2dst[bk * B2CAP + j] == s) {
                        int p = atomicAdd(&sCnt, 1);
                        if (p < MAXDEG) {
                            sXs[p] = tld<F32>(x, b2src[bk * B2CAP + j]);
                            sEa2[p] = b2ea[bk * B2CAP + j];
                        }
                    }
                }
            }
        }
        __syncthreads();
        int deg = sCnt < MAXDEG ? sCnt : MAXDEG;
        for (int i = tid; i < deg; i += THR) {
            float xs = sXs[i], eav = sEa2[i];
            float l0 = 0.f, l1v = 0.f;
            #pragma unroll 8
            for (int c2 = 0; c2 < 128; c2++) {
                float v = xs * sWl[c2] + sBl[c2] + sBase[c2] + eav * sWe[c2];
                v = v > 0.f ? v : NEG_SLOPE * v;
                float w = v * sAtt[c2];
                if (c2 < 64) l0 += w; else l1v += w;
            }
            sL0[i] = l0; sL1[i] = l1v;
        }
        __syncthreads();
        if (tid == 0) {
            float m0 = -1e30f, m1 = -1e30f;
            for (int i = 0; i < deg; i++) { m0 = fmaxf(m0, sL0[i]); m1 = fmaxf(m1, sL1[i]); }
            float s0 = 0.f, s1 = 0.f;
            for (int i = 0; i < deg; i++) {
                sL0[i] = __expf(sL0[i] - m0); s0 += sL0[i];
                sL1[i] = __expf(sL1[i] - m1); s1 += sL1[i];
            }
            float r0 = 1.f / s0, r1 = 1.f / s1;
            for (int i = 0; i < deg; i++) { sL0[i] *= r0; sL1[i] *= r1; }
        }
        __syncthreads();
        if (tid < 128) {
            bool hi = tid >= 64;
            float acc = 0.f;
            for (int i = 0; i < deg; i++) {
                float a = hi ? sL1[i] : sL0[i];
                acc += a * (sXs[i] * sWl[tid] + sBl[tid]);
            }
            acc += sB1[tid];
            sH[tid] = fmaxf(acc, 0.f);
        }
        __syncthreads();
        if (tid < 128) {
            float acc = tld<F32>(bl2, tid);
            #pragma unroll 16
            for (int k = 0; k < 128; k++) acc += sH[k] * tld<F32>(Wl2, k * 128 + tid);
            xl2[bid * 128 + tid] = acc;
            if (s == tgt0) {
                float a2 = tld<F32>(br2, tid);
                #pragma unroll 16
                for (int k = 0; k < 128; k++) a2 += sH[k] * tld<F32>(Wr2, k * 128 + tid);
                xr2[tid] = a2;
            }
        }
        __syncthreads();
        __threadfence();
        if (tid == 0) atomicAdd(&W[4], 1);
    } else if (bid == CAPS) {
        // ---------------- finisher: layer-2 + FC ----------------
        __shared__ float sl0[CAP1], sl1[CAP1];
        __shared__ int sslot[CAP1];
        __shared__ float semb[128];
        __shared__ int sS[CAPS];
        if (tid == 0) {
            while (__hip_atomic_load(&W[4], __ATOMIC_ACQUIRE, __HIP_MEMORY_SCOPE_AGENT) < ns)
                __builtin_amdgcn_s_sleep(2);
        }
        __syncthreads();
        if (tid < ns) sS[tid] = slist[tid];
        __syncthreads();
        for (int e = tid; e < c1; e += THR) {
            int sv = l1src[e];
            int slot = 0;
            for (int j = 0; j < ns; j++) if (sS[j] == sv) { slot = j; break; }
            sslot[e] = slot;
        }
        __syncthreads();
        float xr = 0.f, we = 0.f, at = 0.f;
        if (tid < 128) { xr = ald_f(&xr2[tid]); we = tld<F32>(We2, tid); at = tld<F32>(att2, tid); }
        for (int e = 0; e < c1; e++) {
            float w = 0.f;
            if (tid < 128) {
                float v = ald_f(&xl2[sslot[e] * 128 + tid]) + xr + l1ea[e] * we;
                v = v > 0.f ? v : NEG_SLOPE * v;
                w = v * at;
            }
            for (int o = 32; o > 0; o >>= 1) w += __shfl_down(w, o);
            if (tid == 0)  sl0[e] = w;
            if (tid == 64) sl1[e] = w;
        }
        __syncthreads();
        if (tid == 0) {
            float m0 = -1e30f, m1 = -1e30f;
            for (int e = 0; e < c1; e++) { m0 = fmaxf(m0, sl0[e]); m1 = fmaxf(m1, sl1[e]); }
            float s0 = 0.f, s1 = 0.f;
            for (int e = 0; e < c1; e++) {
                sl0[e] = __expf(sl0[e] - m0); s0 += sl0[e];
                sl1[e] = __expf(sl1[e] - m1); s1 += sl1[e];
            }
            float r0 = 1.f / s0, r1 = 1.f / s1;
            for (int e = 0; e < c1; e++) { sl0[e] *= r0; sl1[e] *= r1; }
        }
        __syncthreads();
        if (tid < 128) {
            bool hi = tid >= 64;
            float acc = tld<F32>(b2v, tid);
            for (int e = 0; e < c1; e++) {
                float a = hi ? sl1[e] : sl0[e];
                acc += a * ald_f(&xl2[sslot[e] * 128 + tid]);
            }
            semb[tid] = acc;
        }
        __syncthreads();
        if (tid < 128) {
            float o = tld<F32>(bfc, tid);
            #pragma unroll 16
            for (int c2 = 0; c2 < 128; c2++) o += semb[c2] * tld<F32>(Wfc, c2 * 128 + tid);
            if (F32) ((float*)out)[tid] = o;
            else     ((__hip_bfloat16*)out)[tid] = __float2bfloat16(o);
        }
    }
}

__global__ void __launch_bounds__(THR)
k_tail(const void* x, const int* tgt,
       const void* Wl1, const void* bl1, const void* Wr1, const void* br1,
       const void* We1, const void* att1, const void* b1,
       const void* Wl2, const void* bl2, const void* Wr2, const void* br2,
       const void* We2, const void* att2, const void* b2v,
       const void* Wfc, const void* bfc,
       void* out, int* W)
{
    int t = tgt[0];
    if (W[3]) tail_body<true >(x, t, Wl1, bl1, Wr1, br1, We1, att1, b1,
                               Wl2, bl2, Wr2, br2, We2, att2, b2v, Wfc, bfc, out, W);
    else      tail_body<false>(x, t, Wl1, bl1, Wr1, br1, We1, att1, b1,
                               Wl2, bl2, Wr2, br2, We2, att2, b2v, Wfc, bfc, out, W);
}

// ---------------------------------------------------------------------------
extern "C" void kernel_launch(void* const* d_in, const int* in_sizes, int n_in,
                              void* d_out, int out_size, void* d_ws, size_t ws_size,
                              hipStream_t stream) {
    const void* x    = d_in[0];
    const int*  eidx = (const int*)d_in[1];
    const void* eattr= d_in[2];
    const int*  tgt  = (const int*)d_in[3];
    const void* Wl1 = d_in[4],  *bl1 = d_in[5],  *Wr1 = d_in[6],  *br1 = d_in[7];
    const void* We1 = d_in[8],  *att1= d_in[9],  *b1  = d_in[10];
    const void* Wl2 = d_in[11], *bl2 = d_in[12], *Wr2 = d_in[13], *br2 = d_in[14];
    const void* We2 = d_in[15], *att2= d_in[16], *b2v = d_in[17];
    const void* Wfc = d_in[18], *bfc = d_in[19];

    int E = in_sizes[1] / 2;
    const int* src = eidx;
    const int* dst = eidx + E;
    int* W = (int*)d_ws;

    k_scan1<<<NB1, THR, 0, stream>>>(x, src, dst, eattr, tgt, E, W);
    k_scan2<<<NB2, THR, 0, stream>>>(src, dst, eattr, tgt, E, W);
    k_tail <<<NTAIL, THR, 0, stream>>>(x, tgt, Wl1, bl1, Wr1, br1, We1, att1, b1,
                                       Wl2, bl2, Wr2, br2, We2, att2, b2v,
                                       Wfc, bfc, d_out, W);
}

// Round 7
// 154.612 us; speedup vs baseline: 2.2533x; 1.2829x over previous
//
#include <hip/hip_runtime.h>
#include <hip/hip_bf16.h>

#define NEG_SLOPE 0.2f
#define THR    256   // threads per block
#define NB1    512   // scan1 blocks
#define NB2    512   // scan2 blocks
#define B1CAP  16    // per-block bucket cap, target edges (exp ~0.04/block)
#define B2CAP  32    // per-block bucket cap, S edges (exp ~1/block)
#define CAP1   512   // total edges into target (realistic ~21)
#define CAPS   64    // unique source nodes incl target (realistic ~21)
#define MAXDEG 256   // per-node in-degree cap in layer-1
#define NTAIL  (CAPS + 1)

// ws header: W[0]=c1 W[1]=ns W[3]=f32 W[4]=doneCnt W[5]=mean(bits)
#define OFF_PARTS  8
#define OFF_B1CNT  (OFF_PARTS + NB1)
#define OFF_B1SRC  (OFF_B1CNT + NB1)
#define OFF_B1EA   (OFF_B1SRC + NB1 * B1CAP)
#define OFF_B2CNT  (OFF_B1EA + NB1 * B1CAP)
#define OFF_B2SRC  (OFF_B2CNT + NB2)
#define OFF_B2DST  (OFF_B2SRC + NB2 * B2CAP)
#define OFF_B2EA   (OFF_B2DST + NB2 * B2CAP)
#define OFF_L1SRC  (OFF_B2EA + NB2 * B2CAP)
#define OFF_L1EA   (OFF_L1SRC + CAP1)
#define OFF_SLIST  (OFF_L1EA + CAP1)
#define OFF_XL2    (OFF_SLIST + CAPS)
#define OFF_XR2    (OFF_XL2 + CAPS * 128)

__device__ __forceinline__ float us2f(unsigned short s) {
    union { unsigned int u; float f; } c;
    c.u = ((unsigned int)s) << 16;
    return c.f;
}
template<bool F32>
__device__ __forceinline__ float tld(const void* p, int i) {
    if (F32) return ((const float*)p)[i];
    return us2f(((const unsigned short*)p)[i]);
}
__device__ __forceinline__ float ald_f(const float* p) {
    return __hip_atomic_load(p, __ATOMIC_RELAXED, __HIP_MEMORY_SCOPE_AGENT);
}

// ---------------------------------------------------------------------------
// K1: dtype detect (per-block) + bucketed scan for dst==target + ea partials.
template<bool F32>
__device__ void scan1_body(const int* __restrict__ src, const int* __restrict__ dst,
                           const void* __restrict__ ea, int t, int E,
                           int* __restrict__ W) {
    __shared__ float sRed[4];
    __shared__ int   sCnt;
    __shared__ int   sIb[B1CAP];
    __shared__ float sFb[B1CAP];
    const int tid = threadIdx.x, bid = blockIdx.x;
    const int gid = bid * THR + tid, gs = NB1 * THR;
    const int E4 = E >> 2, rem = E & 3;
    float* parts = (float*)(W + OFF_PARTS);
    int*   b1cnt = W + OFF_B1CNT;
    int*   b1src = W + OFF_B1SRC;
    float* b1ea  = (float*)(W + OFF_B1EA);

    if (tid == 0) sCnt = 0;
    __syncthreads();
    float sum = 0.f;
    for (int j = gid; j < E4; j += gs) {
        int4 d4 = ((const int4*)dst)[j];
        float v0, v1, v2, v3;
        if (F32) {
            float4 e4 = ((const float4*)ea)[j];
            v0 = e4.x; v1 = e4.y; v2 = e4.z; v3 = e4.w;
        } else {
            ushort4 u4 = ((const ushort4*)ea)[j];
            v0 = us2f(u4.x); v1 = us2f(u4.y); v2 = us2f(u4.z); v3 = us2f(u4.w);
        }
        sum += (v0 + v1) + (v2 + v3);
        int base = 4 * j;
        if (d4.x == t) { int p = atomicAdd(&sCnt, 1); if (p < B1CAP) { sIb[p] = src[base+0]; sFb[p] = v0; } }
        if (d4.y == t) { int p = atomicAdd(&sCnt, 1); if (p < B1CAP) { sIb[p] = src[base+1]; sFb[p] = v1; } }
        if (d4.z == t) { int p = atomicAdd(&sCnt, 1); if (p < B1CAP) { sIb[p] = src[base+2]; sFb[p] = v2; } }
        if (d4.w == t) { int p = atomicAdd(&sCnt, 1); if (p < B1CAP) { sIb[p] = src[base+3]; sFb[p] = v3; } }
    }
    if (gid < rem) {
        int i = E4 * 4 + gid;
        float v = tld<F32>(ea, i);
        sum += v;
        if (dst[i] == t) { int p = atomicAdd(&sCnt, 1); if (p < B1CAP) { sIb[p] = src[i]; sFb[p] = v; } }
    }
    for (int o = 32; o > 0; o >>= 1) sum += __shfl_down(sum, o);
    if ((tid & 63) == 0) sRed[tid >> 6] = sum;
    __syncthreads();
    if (tid == 0) parts[bid] = sRed[0] + sRed[1] + sRed[2] + sRed[3];
    int bc = sCnt < B1CAP ? sCnt : B1CAP;
    if (tid == 0) b1cnt[bid] = bc;
    if (tid < bc) { b1src[bid * B1CAP + tid] = sIb[tid]; b1ea[bid * B1CAP + tid] = sFb[tid]; }
}

__global__ void __launch_bounds__(THR)
k_scan1(const void* __restrict__ x, const int* __restrict__ src,
        const int* __restrict__ dst, const void* __restrict__ ea,
        const int* __restrict__ tgt, int E, int* __restrict__ W) {
    __shared__ int sWeird;
    if (threadIdx.x == 0) sWeird = 0;
    __syncthreads();
    {
        const unsigned short* u = (const unsigned short*)x;
        int c = 0;
        for (int i = threadIdx.x; i < 2048; i += THR) {
            int e2 = (u[i] >> 7) & 0xFF;
            if (e2 == 0 || e2 >= 0xC0) c++;
        }
        for (int o = 32; o > 0; o >>= 1) c += __shfl_down(c, o);
        if ((threadIdx.x & 63) == 0) atomicAdd(&sWeird, c);
    }
    __syncthreads();
    bool f32 = sWeird >= 64;
    if (blockIdx.x == 0 && threadIdx.x == 0) W[3] = f32 ? 1 : 0;
    int t = tgt[0];
    if (f32) scan1_body<true >(src, dst, ea, t, E, W);
    else     scan1_body<false>(src, dst, ea, t, E, W);
}

// ---------------------------------------------------------------------------
// K2: every block builds its own membership list straight from the b1 buckets
//     (duplicates harmless) -> NO cross-block waiting. Bucket-scan edges whose
//     dst is in S. Block 0 afterwards runs the build step (compact l1, mean,
//     dedup slist) for the next kernel.
template<bool F32>
__device__ void scan2_body(const int* __restrict__ src, const int* __restrict__ dst,
                           const void* __restrict__ ea, int tgt0, int E,
                           int* __restrict__ W) {
    __shared__ int   sS[CAPS];
    __shared__ int   sNs, sCnt;
    __shared__ int   sIb[B2CAP], sIb2[B2CAP];
    __shared__ float sFb[B2CAP];
    __shared__ int   sPfx[THR];
    __shared__ float sRed[4];
    const int tid = threadIdx.x, bid = blockIdx.x;
    const int gid = bid * THR + tid, gs = NB2 * THR;
    const int E4 = E >> 2, rem = E & 3;
    float* parts = (float*)(W + OFF_PARTS);
    int*   b1cnt = W + OFF_B1CNT;
    int*   b1src = W + OFF_B1SRC;
    float* b1ea  = (float*)(W + OFF_B1EA);
    int*   b2cnt = W + OFF_B2CNT;
    int*   b2src = W + OFF_B2SRC;
    int*   b2dst = W + OFF_B2DST;
    float* b2ea  = (float*)(W + OFF_B2EA);
    int*   l1src = W + OFF_L1SRC;
    float* l1ea  = (float*)(W + OFF_L1EA);
    int*   slist = W + OFF_SLIST;

    // ---- membership list from raw buckets (incl. target itself) ----
    if (tid == 0) { sS[0] = tgt0; sNs = 1; sCnt = 0; }
    __syncthreads();
    for (int bk = tid; bk < NB1; bk += THR) {
        int c = b1cnt[bk]; if (c > B1CAP) c = B1CAP;
        for (int j = 0; j < c; j++) {
            int p = atomicAdd(&sNs, 1);
            if (p < CAPS) sS[p] = b1src[bk * B1CAP + j];
        }
    }
    __syncthreads();
    int ns = sNs < CAPS ? sNs : CAPS;

    #define CHECK(dv, idx)                                                     \
        do {                                                                   \
            for (int j_ = 0; j_ < ns; j_++) {                                  \
                if (sS[j_] == (dv)) {                                          \
                    int p_ = atomicAdd(&sCnt, 1);                              \
                    if (p_ < B2CAP) {                                          \
                        sIb[p_] = src[idx]; sIb2[p_] = (dv);                   \
                        sFb[p_] = tld<F32>(ea, idx);                           \
                    }                                                          \
                    break;                                                     \
                }                                                              \
            }                                                                  \
        } while (0)
    for (int j = gid; j < E4; j += gs) {
        int4 d4 = ((const int4*)dst)[j];
        int base = 4 * j;
        CHECK(d4.x, base + 0);
        CHECK(d4.y, base + 1);
        CHECK(d4.z, base + 2);
        CHECK(d4.w, base + 3);
    }
    if (gid < rem) { int i = E4 * 4 + gid; CHECK(dst[i], i); }
    #undef CHECK
    __syncthreads();
    int bc = sCnt < B2CAP ? sCnt : B2CAP;
    if (tid == 0) b2cnt[bid] = bc;
    if (tid < bc) {
        b2src[bid * B2CAP + tid] = sIb[tid];
        b2dst[bid * B2CAP + tid] = sIb2[tid];
        b2ea [bid * B2CAP + tid] = sFb[tid];
    }

    // ---- build step (block 0 only; consumed by the NEXT kernel) ----
    if (bid == 0) {
        __syncthreads();
        int c0  = b1cnt[2*tid];    if (c0  > B1CAP) c0  = B1CAP;
        int c1b = b1cnt[2*tid+1];  if (c1b > B1CAP) c1b = B1CAP;
        int c = c0 + c1b;
        sPfx[tid] = c;
        __syncthreads();
        for (int o = 1; o < THR; o <<= 1) {
            int v = (tid >= o) ? sPfx[tid - o] : 0;
            __syncthreads();
            sPfx[tid] += v;
            __syncthreads();
        }
        int base = sPfx[tid] - c;
        int c1tot = sPfx[THR - 1];
        for (int j = 0; j < c0; j++) {
            int p = base + j;
            if (p < CAP1 - 1) { l1src[p] = b1src[2*tid*B1CAP + j]; l1ea[p] = b1ea[2*tid*B1CAP + j]; }
        }
        for (int j = 0; j < c1b; j++) {
            int p = base + c0 + j;
            if (p < CAP1 - 1) { l1src[p] = b1src[(2*tid+1)*B1CAP + j]; l1ea[p] = b1ea[(2*tid+1)*B1CAP + j]; }
        }
        float s = parts[tid] + parts[tid + THR];
        for (int o = 32; o > 0; o >>= 1) s += __shfl_down(s, o);
        if ((tid & 63) == 0) sRed[tid >> 6] = s;
        __syncthreads();
        if (tid == 0) {
            float mean = (sRed[0] + sRed[1] + sRed[2] + sRed[3]) / (float)E;
            int c1 = c1tot < CAP1 - 1 ? c1tot : CAP1 - 1;
            l1src[c1] = tgt0; l1ea[c1] = mean;      // target self-loop
            c1++;
            int nsl = 0;                             // unique S (serial, ~21)
            for (int e = 0; e < c1; e++) {
                int sv = l1src[e];
                bool f = false;
                for (int j = 0; j < nsl; j++) if (sS[j] == sv) { f = true; break; }
                if (!f && nsl < CAPS) { sS[nsl] = sv; nsl++; }
            }
            for (int j = 0; j < nsl; j++) slist[j] = sS[j];
            W[0] = c1; W[1] = nsl; W[4] = 0;
            ((float*)W)[5] = mean;
        }
    }
}

__global__ void __launch_bounds__(THR)
k_scan2(const int* __restrict__ src, const int* __restrict__ dst,
        const void* __restrict__ ea, const int* __restrict__ tgt,
        int E, int* __restrict__ W) {
    int t = tgt[0];
    if (W[3]) scan2_body<true >(src, dst, ea, t, E, W);
    else      scan2_body<false>(src, dst, ea, t, E, W);
}

// ---------------------------------------------------------------------------
// K3: blocks 0..ns-1 = layer-1 per S-node; block CAPS = finisher (layer-2+FC).
template<bool F32>
__device__ void tail_body(
    const void* __restrict__ x, int tgt0,
    const void* Wl1, const void* bl1, const void* Wr1, const void* br1,
    const void* We1, const void* att1, const void* b1,
    const void* Wl2, const void* bl2, const void* Wr2, const void* br2,
    const void* We2, const void* att2, const void* b2v,
    const void* Wfc, const void* bfc,
    void* __restrict__ out, int* __restrict__ W)
{
    const int tid = threadIdx.x, bid = blockIdx.x;
    int*   b2cnt = W + OFF_B2CNT;
    int*   b2src = W + OFF_B2SRC;
    int*   b2dst = W + OFF_B2DST;
    float* b2ea  = (float*)(W + OFF_B2EA);
    int*   l1src = W + OFF_L1SRC;
    float* l1ea  = (float*)(W + OFF_L1EA);
    int*   slist = W + OFF_SLIST;
    float* xl2   = (float*)(W + OFF_XL2);
    float* xr2   = (float*)(W + OFF_XR2);

    int ns = W[1]; if (ns > CAPS) ns = CAPS;
    int c1 = W[0]; if (c1 > CAP1) c1 = CAP1;
    float mean = ((float*)W)[5];

    if (bid < ns) {
        // ---------------- layer-1 for node s ----------------
        __shared__ float sWl[128], sBl[128], sWe[128], sAtt[128], sB1[128], sBase[128];
        __shared__ float sXs[MAXDEG], sEa2[MAXDEG], sL0[MAXDEG], sL1[MAXDEG], sH[128];
        __shared__ int sCnt;
        int s = slist[bid];
        if (tid < 128) {
            sWl[tid] = tld<F32>(Wl1, tid);  sBl[tid] = tld<F32>(bl1, tid);
            sWe[tid] = tld<F32>(We1, tid);  sAtt[tid] = tld<F32>(att1, tid);
            sB1[tid] = tld<F32>(b1, tid);
            float xt = tld<F32>(x, s);
            sBase[tid] = xt * tld<F32>(Wr1, tid) + tld<F32>(br1, tid);
        }
        if (tid == 0) { sCnt = 1; sXs[0] = tld<F32>(x, s); sEa2[0] = mean; }  // self-loop
        __syncthreads();
        for (int bk = tid; bk < NB2; bk += THR) {
            int c = b2cnt[bk]; if (c > B2CAP) c = B2CAP;
            for (int j = 0; j < c; j++) {
                if (b2dst[bk * B2CAP + j] == s) {
                    int p = atomicAdd(&sCnt, 1);
                    if (p < MAXDEG) {
                        sXs[p] = tld<F32>(x, b2src[bk * B2CAP + j]);
                        sEa2[p] = b2ea[bk * B2CAP + j];
                    }
                }
            }
        }
        __syncthreads();
        int deg = sCnt < MAXDEG ? sCnt : MAXDEG;
        for (int i = tid; i < deg; i += THR) {
            float xs = sXs[i], eav = sEa2[i];
            float l0 = 0.f, l1v = 0.f;
            #pragma unroll 8
            for (int c2 = 0; c2 < 128; c2++) {
                float v = xs * sWl[c2] + sBl[c2] + sBase[c2] + eav * sWe[c2];
                v = v > 0.f ? v : NEG_SLOPE * v;
                float w = v * sAtt[c2];
                if (c2 < 64) l0 += w; else l1v += w;
            }
            sL0[i] = l0; sL1[i] = l1v;
        }
        __syncthreads();
        if (tid == 0) {
            float m0 = -1e30f, m1 = -1e30f;
            for (int i = 0; i < deg; i++) { m0 = fmaxf(m0, sL0[i]); m1 = fmaxf(m1, sL1[i]); }
            float s0 = 0.f, s1 = 0.f;
            for (int i = 0; i < deg; i++) {
                sL0[i] = __expf(sL0[i] - m0); s0 += sL0[i];
                sL1[i] = __expf(sL1[i] - m1); s1 += sL1[i];
            }
            float r0 = 1.f / s0, r1 = 1.f / s1;
            for (int i = 0; i < deg; i++) { sL0[i] *= r0; sL1[i] *= r1; }
        }
        __syncthreads();
        if (tid < 128) {
            bool hi = tid >= 64;
            float acc = 0.f;
            for (int i = 0; i < deg; i++) {
                float a = hi ? sL1[i] : sL0[i];
                acc += a * (sXs[i] * sWl[tid] + sBl[tid]);
            }
            acc += sB1[tid];
            sH[tid] = fmaxf(acc, 0.f);
        }
        __syncthreads();
        if (tid < 128) {
            float acc = tld<F32>(bl2, tid);
            #pragma unroll 16
            for (int k = 0; k < 128; k++) acc += sH[k] * tld<F32>(Wl2, k * 128 + tid);
            xl2[bid * 128 + tid] = acc;
            if (s == tgt0) {
                float a2 = tld<F32>(br2, tid);
                #pragma unroll 16
                for (int k = 0; k < 128; k++) a2 += sH[k] * tld<F32>(Wr2, k * 128 + tid);
                xr2[tid] = a2;
            }
        }
        __syncthreads();
        __threadfence();
        if (tid == 0)
            __hip_atomic_fetch_add(&W[4], 1, __ATOMIC_RELEASE, __HIP_MEMORY_SCOPE_AGENT);
    } else if (bid == CAPS) {
        // ---------------- finisher: layer-2 + FC ----------------
        __shared__ float sl0[CAP1], sl1[CAP1];
        __shared__ int sslot[CAP1];
        __shared__ float semb[128];
        __shared__ int sS[CAPS];
        if (tid == 0) {
            // single-thread relaxed poll with backoff (narrow spin: 1 probe line)
            while (__hip_atomic_load(&W[4], __ATOMIC_RELAXED, __HIP_MEMORY_SCOPE_AGENT) < ns)
                __builtin_amdgcn_s_sleep(32);
        }
        __syncthreads();
        __threadfence();
        if (tid < ns) sS[tid] = slist[tid];
        __syncthreads();
        for (int e = tid; e < c1; e += THR) {
            int sv = l1src[e];
            int slot = 0;
            for (int j = 0; j < ns; j++) if (sS[j] == sv) { slot = j; break; }
            sslot[e] = slot;
        }
        __syncthreads();
        float xr = 0.f, we = 0.f, at = 0.f;
        if (tid < 128) { xr = ald_f(&xr2[tid]); we = tld<F32>(We2, tid); at = tld<F32>(att2, tid); }
        for (int e = 0; e < c1; e++) {
            float w = 0.f;
            if (tid < 128) {
                float v = ald_f(&xl2[sslot[e] * 128 + tid]) + xr + l1ea[e] * we;
                v = v > 0.f ? v : NEG_SLOPE * v;
                w = v * at;
            }
            for (int o = 32; o > 0; o >>= 1) w += __shfl_down(w, o);
            if (tid == 0)  sl0[e] = w;
            if (tid == 64) sl1[e] = w;
        }
        __syncthreads();
        if (tid == 0) {
            float m0 = -1e30f, m1 = -1e30f;
            for (int e = 0; e < c1; e++) { m0 = fmaxf(m0, sl0[e]); m1 = fmaxf(m1, sl1[e]); }
            float s0 = 0.f, s1 = 0.f;
            for (int e = 0; e < c1; e++) {
                sl0[e] = __expf(sl0[e] - m0); s0 += sl0[e];
                sl1[e] = __expf(sl1[e] - m1); s1 += sl1[e];
            }
            float r0 = 1.f / s0, r1 = 1.f / s1;
            for (int e = 0; e < c1; e++) { sl0[e] *= r0; sl1[e] *= r1; }
        }
        __syncthreads();
        if (tid < 128) {
            bool hi = tid >= 64;
            float acc = tld<F32>(b2v, tid);
            for (int e = 0; e < c1; e++) {
                float a = hi ? sl1[e] : sl0[e];
                acc += a * ald_f(&xl2[sslot[e] * 128 + tid]);
            }
            semb[tid] = acc;
        }
        __syncthreads();
        if (tid < 128) {
            float o = tld<F32>(bfc, tid);
            #pragma unroll 16
            for (int c2 = 0; c2 < 128; c2++) o += semb[c2] * tld<F32>(Wfc, c2 * 128 + tid);
            if (F32) ((float*)out)[tid] = o;
            else     ((__hip_bfloat16*)out)[tid] = __float2bfloat16(o);
        }
    }
}

__global__ void __launch_bounds__(THR)
k_tail(const void* x, const int* tgt,
       const void* Wl1, const void* bl1, const void* Wr1, const void* br1,
       const void* We1, const void* att1, const void* b1,
       const void* Wl2, const void* bl2, const void* Wr2, const void* br2,
       const void* We2, const void* att2, const void* b2v,
       const void* Wfc, const void* bfc,
       void* out, int* W)
{
    int t = tgt[0];
    if (W[3]) tail_body<true >(x, t, Wl1, bl1, Wr1, br1, We1, att1, b1,
                               Wl2, bl2, Wr2, br2, We2, att2, b2v, Wfc, bfc, out, W);
    else      tail_body<false>(x, t, Wl1, bl1, Wr1, br1, We1, att1, b1,
                               Wl2, bl2, Wr2, br2, We2, att2, b2v, Wfc, bfc, out, W);
}

// ---------------------------------------------------------------------------
extern "C" void kernel_launch(void* const* d_in, const int* in_sizes, int n_in,
                              void* d_out, int out_size, void* d_ws, size_t ws_size,
                              hipStream_t stream) {
    const void* x    = d_in[0];
    const int*  eidx = (const int*)d_in[1];
    const void* eattr= d_in[2];
    const int*  tgt  = (const int*)d_in[3];
    const void* Wl1 = d_in[4],  *bl1 = d_in[5],  *Wr1 = d_in[6],  *br1 = d_in[7];
    const void* We1 = d_in[8],  *att1= d_in[9],  *b1  = d_in[10];
    const void* Wl2 = d_in[11], *bl2 = d_in[12], *Wr2 = d_in[13], *br2 = d_in[14];
    const void* We2 = d_in[15], *att2= d_in[16], *b2v = d_in[17];
    const void* Wfc = d_in[18], *bfc = d_in[19];

    int E = in_sizes[1] / 2;
    const int* src = eidx;
    const int* dst = eidx + E;
    int* W = (int*)d_ws;

    k_scan1<<<NB1, THR, 0, stream>>>(x, src, dst, eattr, tgt, E, W);
    k_scan2<<<NB2, THR, 0, stream>>>(src, dst, eattr, tgt, E, W);
    k_tail <<<NTAIL, THR, 0, stream>>>(x, tgt, Wl1, bl1, Wr1, br1, We1, att1, b1,
                                       Wl2, bl2, Wr2, br2, We2, att2, b2v,
                                       Wfc, bfc, d_out, W);
}